// Round 7
// baseline (86.392 us; speedup 1.0000x reference)
//
#include <hip/hip_runtime.h>
#include <math.h>

#define N_    1024
#define RANK_ 8
#define M_    8192

typedef float vf2 __attribute__((ext_vector_type(2)));

// Static device scratch (~1.1 MB), fully rewritten every call.
__device__ __align__(16) float2 g_Y  [RANK_ * M_];  // DFT stage-1 intermediate
__device__ __align__(16) float  g_Amp[RANK_ * M_];  // |FFT(softplus(H))|
__device__ __align__(16) float  g_Phi[RANK_ * M_];  // arg(FFT)/2pi  (revolutions)
__device__ __align__(16) float  g_sw [N_ * RANK_];  // softmax(W, axis=1)

// v_sin_f32 / v_cos_f32: input in REVOLUTIONS (cdna4_isa.md §3); reduce via fract.
__device__ __forceinline__ float cos2pi(float rev) { return __builtin_amdgcn_cosf(rev); }
__device__ __forceinline__ float sin2pi(float rev) { return __builtin_amdgcn_sinf(rev); }

// ============ kernel A: fused softplus -> stage-1 DFT (blocks 0..255) + softmax(W) (blocks 256..259) ============
// stage 1: Y[r][t1][k2] = sum_t2 softplus(H)[r][t1+64*t2] * W128^(k2*t2),  8192 = 64(t1) x 128(t2)
__global__ __launch_bounds__(256) void k_pre(const float* __restrict__ H,
                                             const float* __restrict__ W) {
    if (blockIdx.x < 256) {
        __shared__ float spl[256];          // spl[h*128+j] = softplus(H[r, 2(b&31)+h + 64*j])
        __shared__ float cs[128], sn[128];  // twiddle table, 128 distinct angles
        int t    = threadIdx.x;
        int b    = blockIdx.x;
        int r    = b >> 5;
        int half = t >> 7;                  // wave-uniform (waves 0,1 -> 0; waves 2,3 -> 1)
        int j    = t & 127;
        int t1   = ((b & 31) << 1) | half;
        float x = H[r * M_ + t1 + (j << 6)];
        spl[half * 128 + j] = (x > 20.f) ? x : log1pf(expf(x));
        if (t < 128) {
            float rev = (float)t * (1.0f / 128.0f);
            cs[t] = cos2pi(rev);
            sn[t] = sin2pi(rev);
        }
        __syncthreads();
        int k2 = j;
        float ar = 0.f, ai = 0.f;
        for (int t2 = 0; t2 < 128; ++t2) {
            float xv = spl[half * 128 + t2];          // wave-uniform -> LDS broadcast
            int id = (k2 * t2) & 127;
            ar = fmaf(xv,  cs[id], ar);               // x * (c - i s)
            ai = fmaf(xv, -sn[id], ai);
        }
        g_Y[b * 256 + t] = make_float2(ar, ai);       // == g_Y[r*8192 + t1*128 + k2]
    } else {
        int n = (blockIdx.x - 256) * 256 + threadIdx.x;
        if (n < N_) {
            float v[RANK_];
            float mx = -1e30f;
#pragma unroll
            for (int r = 0; r < RANK_; ++r) { v[r] = W[n * RANK_ + r]; mx = fmaxf(mx, v[r]); }
            float s = 0.f;
#pragma unroll
            for (int r = 0; r < RANK_; ++r) { v[r] = expf(v[r] - mx); s += v[r]; }
            float inv = 1.f / s;
#pragma unroll
            for (int r = 0; r < RANK_; ++r) g_sw[n * RANK_ + r] = v[r] * inv;
        }
    }
}

// ============ kernel B: stage-2 DFT with rotation recurrence + amp/phase epilogue ============
// Hf[r][k] = sum_t1 Y[r][t1][k&127] * e^{-2pi*i*t1*k/8192}
__global__ void k_dft2() {
    int tid = blockIdx.x * blockDim.x + threadIdx.x;   // 65536 threads
    int k = tid & 8191;
    int r = tid >> 13;
    int j = k & 127;
    const float2* y = g_Y + r * M_ + j;
    float rev = (float)k * (1.0f / 8192.0f);           // exact in fp32
    float cr = cos2pi(rev), sr = sin2pi(rev);
    float c = 1.f, s = 0.f;                            // rotor at t1 = 0
    float ar = 0.f, ai = 0.f;
    for (int t1 = 0; t1 < 64; ++t1) {
        float2 yv = y[t1 * 128];                       // coalesced (lanes j-consecutive)
        // (yr + i*yi) * (c - i*s)
        ar = fmaf(yv.x, c, ar); ar = fmaf(yv.y, s, ar);
        ai = fmaf(yv.y, c, ai); ai = fmaf(-yv.x, s, ai);
        // angle += rev :  cos(a+b) = c*cr - s*sr ; sin(a+b) = s*cr + c*sr
        float cn = fmaf(c, cr, -(s * sr));
        float sn_ = fmaf(s, cr,  (c * sr));
        c = cn; s = sn_;
    }
    g_Amp[tid] = sqrtf(ar * ar + ai * ai);
    g_Phi[tid] = atan2f(ai, ar) * 0.15915494309189535f;  // /(2pi) -> revolutions
}

// ============ kernel C: out[n,m] = sum_r sw[n,r] * A[r,m] * cos(2pi*(tau*f - phi)) ============
// d_out is (N, M) float32 = real part of the complex reference (established R4).
// MT=8: loop/address overhead amortized over 2x elements, 32B stores per row.
// Per element: 1 fma + 1 v_fract + 1 v_cos + 1/2 pk_fma + 1/2 pk_mul.
#define MT 8   // m-values per thread (2x float4 store)
#define NT 8   // n-rows per block
__global__ __launch_bounds__(256) void k_main(const float* __restrict__ tau,
                                              float4* __restrict__ out,
                                              int out_size_floats) {
    int m0 = (blockIdx.x * 256 + threadIdx.x) * MT;
    int n0 = blockIdx.y * NT;
    const float invM = 1.0f / (float)M_;
    vf2 f[4];
#pragma unroll
    for (int j = 0; j < 4; ++j)
        f[j] = (vf2){ (float)(m0 + 2 * j) * invM, (float)(m0 + 2 * j + 1) * invM };

    vf2 acc[NT][4];
#pragma unroll
    for (int i = 0; i < NT; ++i)
#pragma unroll
        for (int j = 0; j < 4; ++j) acc[i][j] = (vf2){0.f, 0.f};

#pragma unroll
    for (int r = 0; r < RANK_; ++r) {
        const float* Ab = &g_Amp[r * M_ + m0];
        const float* Pb = &g_Phi[r * M_ + m0];
        float4 A0 = *reinterpret_cast<const float4*>(Ab);
        float4 A1 = *reinterpret_cast<const float4*>(Ab + 4);
        float4 P0 = *reinterpret_cast<const float4*>(Pb);
        float4 P1 = *reinterpret_cast<const float4*>(Pb + 4);
        vf2 Av[4]  = { {A0.x, A0.y}, {A0.z, A0.w}, {A1.x, A1.y}, {A1.z, A1.w} };
        vf2 nP[4]  = { {-P0.x, -P0.y}, {-P0.z, -P0.w}, {-P1.x, -P1.y}, {-P1.z, -P1.w} };
#pragma unroll
        for (int i = 0; i < NT; ++i) {
            float tv = tau [(n0 + i) * RANK_ + r];   // block-uniform -> s_load
            float wv = g_sw[(n0 + i) * RANK_ + r];
            vf2 tvv = {tv, tv};
            vf2 wvv = {wv, wv};
#pragma unroll
            for (int j = 0; j < 4; ++j) {
                vf2 a = __builtin_elementwise_fma(tvv, f[j], nP[j]);
                vf2 c = { cos2pi(__builtin_amdgcn_fractf(a.x)),
                          cos2pi(__builtin_amdgcn_fractf(a.y)) };
                acc[i][j] = __builtin_elementwise_fma(wvv * Av[j], c, acc[i][j]);
            }
        }
    }
    int max_f4 = out_size_floats >> 2;               // guarded stores: no OOB ever
#pragma unroll
    for (int i = 0; i < NT; ++i) {
        int idx = ((n0 + i) * M_ + m0) >> 2;
        if (idx + 1 < max_f4) {
            float4 o0 = { acc[i][0].x, acc[i][0].y, acc[i][1].x, acc[i][1].y };
            float4 o1 = { acc[i][2].x, acc[i][2].y, acc[i][3].x, acc[i][3].y };
            out[idx]     = o0;
            out[idx + 1] = o1;
        }
    }
}

extern "C" void kernel_launch(void* const* d_in, const int* in_sizes, int n_in,
                              void* d_out, int out_size, void* d_ws, size_t ws_size,
                              hipStream_t stream) {
    const float* W   = (const float*)d_in[0];   // (N, RANK)
    const float* H   = (const float*)d_in[1];   // (RANK, M)
    const float* tau = (const float*)d_in[2];   // (N, RANK)

    float4* out = (float4*)d_out;

    k_pre  <<<dim3(256 + N_ / 256),               dim3(256), 0, stream>>>(H, W);
    k_dft2 <<<dim3((RANK_ * M_) / 256),           dim3(256), 0, stream>>>();
    k_main <<<dim3(M_ / (256 * MT), N_ / NT),     dim3(256), 0, stream>>>(tau, out, out_size);
}